// Round 2
// baseline (269.808 us; speedup 1.0000x reference)
//
#include <hip/hip_runtime.h>
#include <math.h>

// Problem constants (from reference setup_inputs)
#define B_      8
#define F_      64        // features
#define HW_     65536     // 256*256 pixels
#define NSEG    33        // N_OBJECTS + 1
#define NOBJ    32
#define FPB     8         // features per segmax block
#define SLICES  16        // pixel slices per batch
#define PIXB    (HW_ / SLICES)     // 4096 pixels per block
#define BLOCKS_PER_B ((F_ / FPB) * SLICES)   // 128 segmax blocks per batch
// d_ws layout:
//   float part[b][slice][NOBJ][F_] = 8*16*32*64 floats = 1,048,576 B
//   int   cnt[8]                   = ticket counters (memset to 0 per launch)
// part: every slot written unconditionally by exactly one block -> poisoned ws
// harmless. cnt: zeroed by hipMemsetAsync each launch (graph-capturable node).

union SharedU {
    // segmax phase: per-thread-private accumulators acc[f_local][seg][lane].
    // word index = f*1056 + seg*32 + lane -> bank = lane mod 32 for ANY seg:
    // zero bank conflicts, zero atomic contention. Same-wave DS ops retire in
    // order, so the read-max-write chain on repeated ids is safe.
    float acc[FPB * NSEG * 32];               // 33,792 B
    struct {                                   // mlp phase (last block of batch)
        float v[NOBJ * 68];                    // [obj][f], pad 68 (float4 ok)
        float w1s[2 * F_ * 32];                // [d][k], 16 KB
        float w2s[NOBJ * 4];
        float b1s[NOBJ];
        float Cm[NOBJ * 36];                   // i-half dots + b1, pad 36
        float Bm[NOBJ * 36];                   // j-half dots
    } m;                                       // 34,944 B total
};

// Fused kernel: grid = 8 b * 8 fgroup * 16 slice = 1024 blocks, 256 threads,
// 4 blocks/CU (LDS 139.8 KB of 160 KB). Each block does its segmax slice;
// the LAST block to finish within a batch (device-scope ticket) runs the
// whole per-batch MLP, overlapping with segmax blocks of later batches and
// eliminating the second kernel launch.
__global__ __launch_bounds__(256) void fused_kernel(
        const float* __restrict__ enc, const int* __restrict__ masks,
        const float* __restrict__ W1, const float* __restrict__ b1,
        const float* __restrict__ W2, const float* __restrict__ b2,
        float* __restrict__ part, int* __restrict__ cnt,
        float* __restrict__ out_vec, float* __restrict__ out_conn) {
    __shared__ SharedU sh;
    __shared__ int is_last;
    const int tid = threadIdx.x;
    const int blk = blockIdx.x;
    const int b     = blk >> 7;              // 128 blocks per batch
    const int fg    = (blk >> 4) & 7;
    const int slice = blk & 15;

    // ---------------- segmax ----------------
    float* acc = sh.acc;
    for (int i = tid; i < FPB * NSEG * 32; i += 256) acc[i] = -INFINITY;
    __syncthreads();

    const int fl = tid >> 5;      // feature within group: 0..7
    const int l  = tid & 31;      // private lane slot
    float* a = acc + fl * (NSEG * 32) + l;   // + id*32 per element

    const float4* ep = (const float4*)(enc + ((size_t)(b * F_ + fg * FPB + fl)) * HW_
                                       + slice * PIXB) + l;
    const int4*   mp = (const int4*)(masks + (size_t)b * HW_ + slice * PIXB) + l;

    #pragma unroll 8
    for (int c = 0; c < PIXB / 128; ++c) {     // 32 iters, 128 pixels each
        float4 v  = ep[c * 32];
        int4   id = mp[c * 32];
        float o;
        o = a[id.x * 32]; a[id.x * 32] = fmaxf(o, v.x);
        o = a[id.y * 32]; a[id.y * 32] = fmaxf(o, v.y);
        o = a[id.z * 32]; a[id.z * 32] = fmaxf(o, v.z);
        o = a[id.w * 32]; a[id.w * 32] = fmaxf(o, v.w);
    }
    __syncthreads();

    // Reduce 32 lane-copies per (f_local, seg): 256 cells (s=1..32, f=0..7),
    // one per thread; seg 0 dropped at the source.
    {
        float* dst = part + ((size_t)(b * SLICES + slice) * NOBJ) * F_;
        const int f = tid & 7, s = (tid >> 3) + 1;
        const float* row = acc + f * (NSEG * 32) + s * 32;
        float m = -INFINITY;
        #pragma unroll
        for (int k = 0; k < 32; k += 4) {
            float4 q = *(const float4*)(row + k);
            m = fmaxf(m, fmaxf(fmaxf(q.x, q.y), fmaxf(q.z, q.w)));
        }
        dst[(s - 1) * F_ + fg * FPB + f] = m;
    }

    // ---------------- handoff ----------------
    // __syncthreads() drains vmcnt(0): all 256 threads' part-stores complete
    // (at least to this XCD's L2) before tid0's device-scope release fence.
    __syncthreads();
    if (tid == 0) {
        __threadfence();                       // release part to device scope
        int t = atomicAdd(&cnt[b], 1);         // device-scope atomic
        is_last = (t == BLOCKS_PER_B - 1);
    }
    __syncthreads();
    if (!is_last) return;
    __threadfence();                           // acquire: invalidate stale L1/L2

    // ---------------- mlp (one block per batch) ----------------
    float* v   = sh.m.v;
    float* w1s = sh.m.w1s;
    float* w2s = sh.m.w2s;
    float* b1s = sh.m.b1s;
    float* Cm  = sh.m.Cm;
    float* Bm  = sh.m.Bm;

    // Stage weights.
    for (int i = tid; i < 2 * F_ * 32 / 4; i += 256)
        ((float4*)w1s)[i] = ((const float4*)W1)[i];
    if (tid < 32) { w2s[tid*4+0]=W2[tid*4+0]; w2s[tid*4+1]=W2[tid*4+1];
                    w2s[tid*4+2]=W2[tid*4+2]; w2s[tid*4+3]=W2[tid*4+3];
                    b1s[tid] = b1[tid]; }

    // Slice-reduce, float4 over f: 512 cell4s (s=0..31, f4=0..15), 2/thread.
    const float4* p4 = (const float4*)(part + (size_t)b * SLICES * NOBJ * F_);
    for (int cell = tid; cell < NOBJ * 16; cell += 256) {
        const int s = cell >> 4, f4 = cell & 15;
        float4 m = {-INFINITY, -INFINITY, -INFINITY, -INFINITY};
        #pragma unroll
        for (int sl = 0; sl < SLICES; ++sl) {
            float4 q = p4[((size_t)sl * NOBJ + s) * (F_ / 4) + f4];
            m.x = fmaxf(m.x, q.x); m.y = fmaxf(m.y, q.y);
            m.z = fmaxf(m.z, q.z); m.w = fmaxf(m.w, q.w);
        }
        *(float4*)(v + s * 68 + f4 * 4) = m;
        ((float4*)(out_vec + (size_t)b * NOBJ * F_))[cell] = m;
    }
    __syncthreads();

    // 512 length-64 float4-dots, 2/thread: half0 -> Cm (i-side, +b1),
    // half1 -> Bm (j-side). w1s reads broadcast within 8-lane kg groups;
    // v reads hit 8 distinct banks (obj stride 68 -> 4 banks apart).
    for (int d = tid; d < 512; d += 256) {
        const int half = d >> 8;
        const int obj  = (d >> 3) & 31;
        const int kg   = d & 7;
        const float* vv = v + obj * 68;
        const float* w  = w1s + half * (F_ * 32) + kg * 4;
        float4 s4 = {0.f, 0.f, 0.f, 0.f};
        #pragma unroll
        for (int f = 0; f < F_; ++f) {
            float4 wf = *(const float4*)(w + f * 32);
            float x = vv[f];
            s4.x = fmaf(x, wf.x, s4.x); s4.y = fmaf(x, wf.y, s4.y);
            s4.z = fmaf(x, wf.z, s4.z); s4.w = fmaf(x, wf.w, s4.w);
        }
        if (half == 0) {
            float4 bb = *(const float4*)(b1s + kg * 4);
            s4.x += bb.x; s4.y += bb.y; s4.z += bb.z; s4.w += bb.w;
            *(float4*)(Cm + obj * 36 + kg * 4) = s4;
        } else {
            *(float4*)(Bm + obj * 36 + kg * 4) = s4;
        }
    }
    __syncthreads();

    // 1024 (i,j) pairs, 4/thread: h = Cm_i + Bm_j, out = sigmoid(h@W2 + b2),
    // connections[b][c][j][i] = out[i][j][c].
    {
        const int j  = tid & 31;
        const int i0 = tid >> 5;
        const float bb0 = b2[0], bb1 = b2[1], bb2 = b2[2], bb3 = b2[3];
        #pragma unroll
        for (int k = 0; k < 4; ++k) {
            const int i = i0 + k * 8;
            float o0 = bb0, o1 = bb1, o2 = bb2, o3 = bb3;
            #pragma unroll
            for (int kg = 0; kg < 8; ++kg) {
                float4 ha = *(const float4*)(Cm + i * 36 + kg * 4);
                float4 hb = *(const float4*)(Bm + j * 36 + kg * 4);
                float h0 = ha.x + hb.x, h1 = ha.y + hb.y;
                float h2 = ha.z + hb.z, h3 = ha.w + hb.w;
                const float* w2 = w2s + kg * 16;
                o0 = fmaf(h0, w2[0],  fmaf(h1, w2[4],  fmaf(h2, w2[8],  fmaf(h3, w2[12], o0))));
                o1 = fmaf(h0, w2[1],  fmaf(h1, w2[5],  fmaf(h2, w2[9],  fmaf(h3, w2[13], o1))));
                o2 = fmaf(h0, w2[2],  fmaf(h1, w2[6],  fmaf(h2, w2[10], fmaf(h3, w2[14], o2))));
                o3 = fmaf(h0, w2[3],  fmaf(h1, w2[7],  fmaf(h2, w2[11], fmaf(h3, w2[15], o3))));
            }
            float* oc = out_conn + (size_t)b * 4 * NOBJ * NOBJ + j * NOBJ + i;
            oc[0 * NOBJ * NOBJ] = 1.f / (1.f + expf(-o0));
            oc[1 * NOBJ * NOBJ] = 1.f / (1.f + expf(-o1));
            oc[2 * NOBJ * NOBJ] = 1.f / (1.f + expf(-o2));
            oc[3 * NOBJ * NOBJ] = 1.f / (1.f + expf(-o3));
        }
    }
}

extern "C" void kernel_launch(void* const* d_in, const int* in_sizes, int n_in,
                              void* d_out, int out_size, void* d_ws, size_t ws_size,
                              hipStream_t stream) {
    const float* enc   = (const float*)d_in[0];
    const int*   masks = (const int*)  d_in[1];
    const float* W1    = (const float*)d_in[2];
    const float* b1    = (const float*)d_in[3];
    const float* W2    = (const float*)d_in[4];
    const float* b2    = (const float*)d_in[5];

    float* out_vec  = (float*)d_out;                 // 8*32*64 = 16384 floats
    float* out_conn = out_vec + B_ * NOBJ * F_;      // 8*4*32*32 = 32768 floats
    float* part     = (float*)d_ws;                  // 1,048,576 B slice partials
    int*   cnt      = (int*)((char*)d_ws + (size_t)B_ * SLICES * NOBJ * F_ * 4);

    hipMemsetAsync(cnt, 0, B_ * sizeof(int), stream);   // graph-capturable node
    fused_kernel<<<B_ * BLOCKS_PER_B, 256, 0, stream>>>(
        enc, masks, W1, b1, W2, b2, part, cnt, out_vec, out_conn);
}

// Round 4
// 213.423 us; speedup vs baseline: 1.2642x; 1.2642x over previous
//
#include <hip/hip_runtime.h>
#include <math.h>

// Problem constants (from reference setup_inputs)
#define B_      8
#define F_      64        // features
#define HW_     65536     // 256*256 pixels
#define NSEG    33        // N_OBJECTS + 1
#define NOBJ    32
#define FPB     8         // features per segmax block
#define SLICES  16        // pixel slices per batch
#define PIXB    (HW_ / SLICES)     // 4096 pixels per block
// d_ws layout: float part[b][slice][NOBJ][F_] = 8*16*32*64 floats = 1,048,576 B.
// Every slot is written unconditionally by exactly one block -> no init pass,
// poisoned ws is harmless. Segment 0 (background) never stored; mlp reads 1..32.

// Monotone float<->uint key: preserves order under unsigned max.
// x >= 0: key = bits | 0x80000000 ; x < 0: key = ~bits.
__device__ __forceinline__ unsigned fkey(float x) {
    unsigned b = __float_as_uint(x);
    unsigned m = (unsigned)((int)b >> 31) | 0x80000000u;
    return b ^ m;
}
__device__ __forceinline__ float funkey(unsigned k) {
    unsigned m = ((int)k < 0) ? 0x80000000u : 0xFFFFFFFFu;
    return __uint_as_float(k ^ m);
}

// segmax: grid = 8 b * 8 fgroup * 16 slice = 1024 blocks, 256 threads,
// 4 blocks/CU (LDS-limited). Per-thread-PRIVATE LDS accumulators
// acc[f_local][seg][lane]: word index = f*1056 + seg*32 + lane -> bank =
// lane mod 32 for ANY seg: zero bank conflicts by construction.
// Inner loop uses ONE no-return ds_max_u32 per pixel (monotone-key max)
// instead of a dependent ds_read/fmax/ds_write pair: halves DS-pipe issue
// (the co-limiting resource alongside the LLC/HBM stream) and removes the
// LDS dependency chain.
__global__ __launch_bounds__(256) void segmax_kernel(
        const float* __restrict__ enc, const int* __restrict__ masks,
        float* __restrict__ part) {
    __shared__ unsigned acc[FPB * NSEG * 32];   // 33,792 B
    const int tid = threadIdx.x;
    const int blk = blockIdx.x;
    const int b     = blk >> 7;              // 8 fgroups * 16 slices = 128 per b
    const int fg    = (blk >> 4) & 7;
    const int slice = blk & 15;

    for (int i = tid; i < FPB * NSEG * 32; i += 256) acc[i] = 0u;  // key(-inf)-
    __syncthreads();                                               // below-all

    const int fl = tid >> 5;      // feature within group: 0..7
    const int l  = tid & 31;      // private lane slot
    unsigned* a = acc + fl * (NSEG * 32) + l;   // + id*32 per element

    const float4* ep = (const float4*)(enc + ((size_t)(b * F_ + fg * FPB + fl)) * HW_
                                       + slice * PIXB) + l;
    const int4*   mp = (const int4*)(masks + (size_t)b * HW_ + slice * PIXB) + l;

    #pragma unroll 8
    for (int c = 0; c < PIXB / 128; ++c) {     // 32 iters, 128 pixels each
        float4 v  = ep[c * 32];
        int4   id = mp[c * 32];
        atomicMax(a + id.x * 32, fkey(v.x));   // ds_max_u32, no return
        atomicMax(a + id.y * 32, fkey(v.y));
        atomicMax(a + id.z * 32, fkey(v.z));
        atomicMax(a + id.w * 32, fkey(v.w));
    }
    __syncthreads();

    // Reduce 32 lane-copies per (f_local, seg): 256 cells (s=1..32, f=0..7),
    // one per thread; seg 0 dropped at the source. key==0 -> segment absent
    // in this slice -> -inf partial (same as before).
    {
        float* dst = part + ((size_t)(b * SLICES + slice) * NOBJ) * F_;
        const int f = tid & 7, s = (tid >> 3) + 1;
        const unsigned* row = acc + f * (NSEG * 32) + s * 32;
        unsigned m = 0u;
        #pragma unroll
        for (int k = 0; k < 32; k += 4) {
            uint4 q = *(const uint4*)(row + k);
            m = max(m, max(max(q.x, q.y), max(q.z, q.w)));
        }
        dst[(s - 1) * F_ + fg * FPB + f] = (m == 0u) ? -INFINITY : funkey(m);
    }
}

// mlp: grid = 8 b * 4 i-tiles = 32 blocks. Reduces the 16 slice partials
// (float4-vectorized), writes vectors, then h = A_i + B_j + b1,
// out = sigmoid(h@W2 + b2), connections[b][c][j][i] = out[i][j][c].
__global__ __launch_bounds__(256) void mlp_kernel(
        const float* __restrict__ part,
        const float* __restrict__ W1, const float* __restrict__ b1,
        const float* __restrict__ W2, const float* __restrict__ b2,
        float* __restrict__ out_vec, float* __restrict__ out_conn) {
    const int b   = blockIdx.x >> 2;
    const int it  = blockIdx.x & 3;          // i-tile: i = it*8 .. it*8+7
    const int tid = threadIdx.x;
    __shared__ float v[NOBJ * 68];           // [obj][f], pad 68: float4 stores
    __shared__ float w1s[2 * F_ * 32];       // [d][k], 16 KB
    __shared__ float w2s[32 * 4];
    __shared__ float b1s[32];
    __shared__ float Am[8 * 36];             // [i_loc][k], pad 36 (f4-aligned)
    __shared__ float Bm[NOBJ * 36];

    for (int i = tid; i < 2 * F_ * 32 / 4; i += 256)
        ((float4*)w1s)[i] = ((const float4*)W1)[i];
    if (tid < 32) { w2s[tid*4+0]=W2[tid*4+0]; w2s[tid*4+1]=W2[tid*4+1];
                    w2s[tid*4+2]=W2[tid*4+2]; w2s[tid*4+3]=W2[tid*4+3];
                    b1s[tid] = b1[tid]; }

    // Slice-reduce, float4 over f: 512 cell4s (s=0..31, f4=0..15), 2/thread.
    const float4* p4 = (const float4*)(part + (size_t)b * SLICES * NOBJ * F_);
    for (int cell = tid; cell < NOBJ * 16; cell += 256) {
        const int s = cell >> 4, f4 = cell & 15;
        float4 m = {-INFINITY, -INFINITY, -INFINITY, -INFINITY};
        #pragma unroll
        for (int sl = 0; sl < SLICES; ++sl) {
            float4 q = p4[((size_t)sl * NOBJ + s) * (F_ / 4) + f4];
            m.x = fmaxf(m.x, q.x); m.y = fmaxf(m.y, q.y);
            m.z = fmaxf(m.z, q.z); m.w = fmaxf(m.w, q.w);
        }
        *(float4*)(v + s * 68 + f4 * 4) = m;
        if (it == 0) ((float4*)(out_vec + (size_t)b * NOBJ * F_))[cell] = m;
    }
    __syncthreads();

    // 1280 length-64 dots as 320 float4-dots: d<64 -> Am (8 i_loc x 8 kg),
    // d>=64 -> Bm (32 j x 8 kg). Broadcast-friendly LDS access.
    for (int d = tid; d < 320; d += 256) {
        int kg, obj, half;
        if (d < 64) { half = 0; obj = it * 8 + (d >> 3); kg = d & 7; }
        else        { half = 1; obj = (d - 64) >> 3;     kg = d & 7; }
        const float* vv = v + obj * 68;
        const float* w  = w1s + half * (F_ * 32) + kg * 4;
        float4 s4 = {0.f, 0.f, 0.f, 0.f};
        #pragma unroll
        for (int f = 0; f < F_; ++f) {
            float4 wf = *(const float4*)(w + f * 32);
            float x = vv[f];
            s4.x = fmaf(x, wf.x, s4.x); s4.y = fmaf(x, wf.y, s4.y);
            s4.z = fmaf(x, wf.z, s4.z); s4.w = fmaf(x, wf.w, s4.w);
        }
        if (half == 0) {
            float4 bb = *(const float4*)(b1s + kg * 4);
            s4.x += bb.x; s4.y += bb.y; s4.z += bb.z; s4.w += bb.w;
            *(float4*)(Am + (d >> 3) * 36 + kg * 4) = s4;
        } else {
            *(float4*)(Bm + obj * 36 + kg * 4) = s4;
        }
    }
    __syncthreads();

    // 256 (i,j) pairs: one per thread.
    {
        int i_loc = tid >> 5, j = tid & 31;
        float o0 = b2[0], o1 = b2[1], o2 = b2[2], o3 = b2[3];
        #pragma unroll
        for (int kg = 0; kg < 8; ++kg) {
            float4 ha = *(const float4*)(Am + i_loc * 36 + kg * 4);
            float4 hb = *(const float4*)(Bm + j * 36 + kg * 4);
            float h0 = ha.x + hb.x, h1 = ha.y + hb.y;
            float h2 = ha.z + hb.z, h3 = ha.w + hb.w;
            const float* w2 = w2s + kg * 16;
            o0 = fmaf(h0, w2[0],  fmaf(h1, w2[4],  fmaf(h2, w2[8],  fmaf(h3, w2[12], o0))));
            o1 = fmaf(h0, w2[1],  fmaf(h1, w2[5],  fmaf(h2, w2[9],  fmaf(h3, w2[13], o1))));
            o2 = fmaf(h0, w2[2],  fmaf(h1, w2[6],  fmaf(h2, w2[10], fmaf(h3, w2[14], o2))));
            o3 = fmaf(h0, w2[3],  fmaf(h1, w2[7],  fmaf(h2, w2[11], fmaf(h3, w2[15], o3))));
        }
        float* oc = out_conn + (size_t)b * 4 * NOBJ * NOBJ + j * NOBJ + (it * 8 + i_loc);
        oc[0 * NOBJ * NOBJ] = 1.f / (1.f + expf(-o0));
        oc[1 * NOBJ * NOBJ] = 1.f / (1.f + expf(-o1));
        oc[2 * NOBJ * NOBJ] = 1.f / (1.f + expf(-o2));
        oc[3 * NOBJ * NOBJ] = 1.f / (1.f + expf(-o3));
    }
}

extern "C" void kernel_launch(void* const* d_in, const int* in_sizes, int n_in,
                              void* d_out, int out_size, void* d_ws, size_t ws_size,
                              hipStream_t stream) {
    const float* enc   = (const float*)d_in[0];
    const int*   masks = (const int*)  d_in[1];
    const float* W1    = (const float*)d_in[2];
    const float* b1    = (const float*)d_in[3];
    const float* W2    = (const float*)d_in[4];
    const float* b2    = (const float*)d_in[5];

    float* out_vec  = (float*)d_out;                 // 8*32*64 = 16384 floats
    float* out_conn = out_vec + B_ * NOBJ * F_;      // 8*4*32*32 = 32768 floats
    float* part     = (float*)d_ws;                  // 1,048,576 B slice partials

    segmax_kernel<<<B_ * (F_ / FPB) * SLICES, 256, 0, stream>>>(enc, masks, part);
    mlp_kernel<<<B_ * 4, 256, 0, stream>>>(part, W1, b1, W2, b2, out_vec, out_conn);
}

// Round 5
// 207.791 us; speedup vs baseline: 1.2985x; 1.0271x over previous
//
#include <hip/hip_runtime.h>
#include <math.h>

// Problem constants (from reference setup_inputs)
#define B_      8
#define F_      64        // features
#define HW_     65536     // 256*256 pixels
#define NSEG    33        // N_OBJECTS + 1
#define NOBJ    32
#define FPB     8         // features per segmax block
#define SLICES  8         // pixel slices per batch
#define PIXB    (HW_ / SLICES)   // 8192 pixels per block
// d_ws layout: float part[b][slice][NSEG][F_]  = 8*8*33*64 floats = 540,672 B.
// Every slot is written unconditionally by exactly one block -> no init pass,
// no atomics, poisoned ws is harmless.
//
// Session verdict (5 measured variants): this structure is the best at
// 208.7-209.3 us. 2x occupancy (SLICES=16): null. ds_max_u32 (half DS issue):
// +4 us (LDS atomic RMW throughput < read+write pair). Ticket-fusion: +60 us
// (VGPR 204 kills streaming occupancy; per-block device fence = L2 writeback).
// segmax is memory/latency-bound at the mixed LLC/HBM rate; the timed graph
// is dominated by 2x 512 MiB harness poison fills (~155 us fixed).

// segmax: grid = 8 b * 8 fgroup * 8 slice = 512 blocks, 256 threads.
// Per-thread-PRIVATE LDS accumulators acc[f_local][seg][lane]: address word
// index = f*1056 + seg*32 + lane  -> bank = lane mod 32 for ANY seg: zero
// bank conflicts, zero atomic contention by construction. Same-wave DS ops
// retire in order, so read-max-write on repeated ids is safe.
__global__ __launch_bounds__(256) void segmax_kernel(
        const float* __restrict__ enc, const int* __restrict__ masks,
        float* __restrict__ part) {
    __shared__ float acc[FPB * NSEG * 32];   // 33,792 B
    const int tid = threadIdx.x;
    const int blk = blockIdx.x;
    const int b     = blk >> 6;
    const int fg    = (blk >> 3) & 7;
    const int slice = blk & 7;

    for (int i = tid; i < FPB * NSEG * 32; i += 256) acc[i] = -INFINITY;
    __syncthreads();

    const int fl = tid >> 5;      // feature within group: 0..7
    const int l  = tid & 31;      // private lane slot
    float* a = acc + fl * (NSEG * 32) + l;   // + id*32 per element

    const float4* ep = (const float4*)(enc + ((size_t)(b * F_ + fg * FPB + fl)) * HW_
                                       + slice * PIXB) + l;
    const int4*   mp = (const int4*)(masks + (size_t)b * HW_ + slice * PIXB) + l;

    #pragma unroll 8
    for (int c = 0; c < PIXB / 128; ++c) {     // 64 iters, 128 pixels each
        float4 v  = ep[c * 32];
        int4   id = mp[c * 32];
        float o;
        o = a[id.x * 32]; a[id.x * 32] = fmaxf(o, v.x);
        o = a[id.y * 32]; a[id.y * 32] = fmaxf(o, v.y);
        o = a[id.z * 32]; a[id.z * 32] = fmaxf(o, v.z);
        o = a[id.w * 32]; a[id.w * 32] = fmaxf(o, v.w);
    }
    __syncthreads();

    // Reduce 32 lane-copies per (f_local, seg); write per-slice partial max.
    float* dst = part + (((size_t)b * SLICES + slice) * NSEG) * F_;
    for (int cell = tid; cell < FPB * NSEG; cell += 256) {
        int f = cell & 7, s = cell >> 3;
        const float* row = acc + f * (NSEG * 32) + s * 32;
        float m = -INFINITY;
        #pragma unroll
        for (int k = 0; k < 32; k += 4) {
            float4 q = *(const float4*)(row + k);
            m = fmaxf(m, fmaxf(fmaxf(q.x, q.y), fmaxf(q.z, q.w)));
        }
        dst[s * F_ + fg * FPB + f] = m;
    }
}

// mlp: grid = 8 b * 4 i-tiles = 32 blocks. Reduces the 8 slice partials,
// writes vectors, then h = A_i + B_j + b1, out = sigmoid(h@W2 + b2),
// connections[b][c][j][i] = out[i][j][c]. All weights staged in LDS.
__global__ __launch_bounds__(256) void mlp_kernel(
        const float* __restrict__ part,
        const float* __restrict__ W1, const float* __restrict__ b1,
        const float* __restrict__ W2, const float* __restrict__ b2,
        float* __restrict__ out_vec, float* __restrict__ out_conn) {
    const int b   = blockIdx.x >> 2;
    const int it  = blockIdx.x & 3;          // i-tile: i = it*8 .. it*8+7
    const int tid = threadIdx.x;
    __shared__ float v[NOBJ * 65];           // [obj][f], pad 65 kills i-aliasing
    __shared__ float w1s[2 * F_ * 32];       // [d][k], 16 KB
    __shared__ float w2s[32 * 4];
    __shared__ float b1s[32];
    __shared__ float Am[8 * 36];             // [i_loc][k], pad 36 (f4-aligned)
    __shared__ float Bm[NOBJ * 36];

    for (int i = tid; i < 2 * F_ * 32 / 4; i += 256)
        ((float4*)w1s)[i] = ((const float4*)W1)[i];
    if (tid < 32) { w2s[tid*4+0]=W2[tid*4+0]; w2s[tid*4+1]=W2[tid*4+1];
                    w2s[tid*4+2]=W2[tid*4+2]; w2s[tid*4+3]=W2[tid*4+3];
                    b1s[tid] = b1[tid]; }

    // Slice-reduce: cells (s,f) for s=1..32, f=0..63. Coalesced over f.
    for (int cell = tid; cell < NOBJ * F_; cell += 256) {
        int s = (cell >> 6) + 1, f = cell & 63;
        float m = -INFINITY;
        #pragma unroll
        for (int sl = 0; sl < SLICES; ++sl)
            m = fmaxf(m, part[(((size_t)b * SLICES + sl) * NSEG + s) * F_ + f]);
        v[(s - 1) * 65 + f] = m;
        if (it == 0) out_vec[b * NOBJ * F_ + cell] = m;
    }
    __syncthreads();

    // 1280 length-64 dots as 320 float4-dots: d<64 -> Am (8 i_loc x 8 kg),
    // d>=64 -> Bm (32 j x 8 kg). Broadcast-friendly LDS access.
    for (int d = tid; d < 320; d += 256) {
        int kg, obj, half;
        if (d < 64) { half = 0; obj = it * 8 + (d >> 3); kg = d & 7; }
        else        { half = 1; obj = (d - 64) >> 3;     kg = d & 7; }
        const float* vv = v + obj * 65;
        const float* w  = w1s + half * (F_ * 32) + kg * 4;
        float4 s4 = {0.f, 0.f, 0.f, 0.f};
        #pragma unroll
        for (int f = 0; f < F_; ++f) {
            float4 wf = *(const float4*)(w + f * 32);
            float x = vv[f];
            s4.x = fmaf(x, wf.x, s4.x); s4.y = fmaf(x, wf.y, s4.y);
            s4.z = fmaf(x, wf.z, s4.z); s4.w = fmaf(x, wf.w, s4.w);
        }
        if (half == 0) {
            float4 bb = *(const float4*)(b1s + kg * 4);
            s4.x += bb.x; s4.y += bb.y; s4.z += bb.z; s4.w += bb.w;
            *(float4*)(Am + (d >> 3) * 36 + kg * 4) = s4;
        } else {
            *(float4*)(Bm + obj * 36 + kg * 4) = s4;
        }
    }
    __syncthreads();

    // 256 (i,j) pairs: one per thread.
    {
        int i_loc = tid >> 5, j = tid & 31;
        float o0 = b2[0], o1 = b2[1], o2 = b2[2], o3 = b2[3];
        #pragma unroll
        for (int kg = 0; kg < 8; ++kg) {
            float4 ha = *(const float4*)(Am + i_loc * 36 + kg * 4);
            float4 hb = *(const float4*)(Bm + j * 36 + kg * 4);
            float h0 = ha.x + hb.x, h1 = ha.y + hb.y;
            float h2 = ha.z + hb.z, h3 = ha.w + hb.w;
            const float* w2 = w2s + kg * 16;
            o0 = fmaf(h0, w2[0],  fmaf(h1, w2[4],  fmaf(h2, w2[8],  fmaf(h3, w2[12], o0))));
            o1 = fmaf(h0, w2[1],  fmaf(h1, w2[5],  fmaf(h2, w2[9],  fmaf(h3, w2[13], o1))));
            o2 = fmaf(h0, w2[2],  fmaf(h1, w2[6],  fmaf(h2, w2[10], fmaf(h3, w2[14], o2))));
            o3 = fmaf(h0, w2[3],  fmaf(h1, w2[7],  fmaf(h2, w2[11], fmaf(h3, w2[15], o3))));
        }
        float* oc = out_conn + (size_t)b * 4 * NOBJ * NOBJ + j * NOBJ + (it * 8 + i_loc);
        oc[0 * NOBJ * NOBJ] = 1.f / (1.f + expf(-o0));
        oc[1 * NOBJ * NOBJ] = 1.f / (1.f + expf(-o1));
        oc[2 * NOBJ * NOBJ] = 1.f / (1.f + expf(-o2));
        oc[3 * NOBJ * NOBJ] = 1.f / (1.f + expf(-o3));
    }
}

extern "C" void kernel_launch(void* const* d_in, const int* in_sizes, int n_in,
                              void* d_out, int out_size, void* d_ws, size_t ws_size,
                              hipStream_t stream) {
    const float* enc   = (const float*)d_in[0];
    const int*   masks = (const int*)  d_in[1];
    const float* W1    = (const float*)d_in[2];
    const float* b1    = (const float*)d_in[3];
    const float* W2    = (const float*)d_in[4];
    const float* b2    = (const float*)d_in[5];

    float* out_vec  = (float*)d_out;                 // 8*32*64 = 16384 floats
    float* out_conn = out_vec + B_ * NOBJ * F_;      // 8*4*32*32 = 32768 floats
    float* part     = (float*)d_ws;                  // 540,672 B slice partials

    segmax_kernel<<<B_ * SLICES * (F_ / FPB), 256, 0, stream>>>(enc, masks, part);
    mlp_kernel<<<B_ * 4, 256, 0, stream>>>(part, W1, b1, W2, b2, out_vec, out_conn);
}